// Round 2
// baseline (279.692 us; speedup 1.0000x reference)
//
#include <hip/hip_runtime.h>
#include <math.h>

#define BB 8
#define NN 256
#define DD 128
#define EE 64

// One block per (b,i). 256 threads. LDS ~60 KB -> 2 blocks/CU.
__global__ __launch_bounds__(256, 2)
void ecgc_fused(const float* __restrict__ h_g,
                const float* __restrict__ ef_g,
                const int*   __restrict__ mask_g,
                const float* __restrict__ W1_g,
                const float* __restrict__ b1_g,
                const float* __restrict__ W2_g,
                const float* __restrict__ b2_g,
                const float* __restrict__ U1_g,
                const float* __restrict__ b3_g,
                const float* __restrict__ U2_g,
                const float* __restrict__ b4_g,
                const float* __restrict__ gam_g,
                const float* __restrict__ bet_g,
                float*       __restrict__ out_g)
{
    const int bi = blockIdx.x;     // b*N + i
    const int t  = threadIdx.x;    // 0..255

    __shared__ __align__(16) union {
        float W2[EE * DD];          // 32 KB, used during gate GEMM
        float red[3][16 * DD];      // 24 KB, used for j-group reduction after
    } su;
    __shared__ __align__(16) float sh_t[64 * 68];   // t-tile [e][cj], stride 68
    __shared__ __align__(16) float sh_ef[NN * 4];   // edge feats padded to float4
    __shared__ float sh_h[DD];
    __shared__ float sh_base[EE];
    __shared__ float sh_w1e[3 * EE];
    __shared__ float sh_b2[DD];
    __shared__ int   sh_jlist[NN];
    __shared__ int   sh_wcnt[4];
    __shared__ int   sh_cnt;
    __shared__ float sh_upd[3 * DD];
    __shared__ float sh_r[DD];
    __shared__ float sh_x[DD];

    // ---------------- stage ----------------
    if (t < DD) {
        sh_h[t]  = h_g[bi * DD + t];
        sh_b2[t] = b2_g[t];
    }
    {   // edge-feature row (256 x 3) -> float4-padded
        const float* efr = ef_g + (size_t)bi * NN * 3;
        sh_ef[t * 4 + 0] = efr[t * 3 + 0];
        sh_ef[t * 4 + 1] = efr[t * 3 + 1];
        sh_ef[t * 4 + 2] = efr[t * 3 + 2];
        sh_ef[t * 4 + 3] = 0.f;
    }
    for (int idx = t; idx < (EE * DD) / 4; idx += 256)
        ((float4*)su.W2)[idx] = ((const float4*)W2_g)[idx];

    // mask load + ballot-based compaction of masked j's
    const int wave = t >> 6, lane = t & 63;
    const int m = (mask_g[bi * NN + t] != 0) ? 1 : 0;
    const unsigned long long bal = __ballot(m);
    const int pre = __popcll(bal & ((1ull << lane) - 1ull));
    if (lane == 0) sh_wcnt[wave] = __popcll(bal);
    __syncthreads();

    {
        int wbase = 0;
        for (int w = 0; w < wave; ++w) wbase += sh_wcnt[w];
        if (m) sh_jlist[wbase + pre] = t;
        if (t == 0) sh_cnt = sh_wcnt[0] + sh_wcnt[1] + sh_wcnt[2] + sh_wcnt[3];
    }

    // base[e] = b1[e] + h . W1[:128,e]  (j-invariant part); w1e = W1[128:131,:]
    if (t < EE) {
        float acc = b1_g[t];
        #pragma unroll 4
        for (int d = 0; d < DD; ++d)
            acc = fmaf(sh_h[d], W1_g[d * EE + t], acc);
        sh_base[t] = acc;
    } else {
        const int u = t - EE;            // 0..191 == 3*64
        sh_w1e[u] = W1_g[(DD + (u >> 6)) * EE + (u & 63)];
    }
    __syncthreads();

    const int cnt    = sh_cnt;
    const int nchunk = (cnt + 63) >> 6;
    const int dg = t & 15;               // 16 d-groups x 8 d
    const int jg = t >> 4;               // 16 j-groups x 4 j

    float b2r[8];
    #pragma unroll
    for (int k = 0; k < 8; ++k) b2r[k] = sh_b2[dg * 8 + k];

    float sumv[8], maxv[8], minv[8];
    #pragma unroll
    for (int k = 0; k < 8; ++k) { sumv[k] = 0.f; maxv[k] = -INFINITY; minv[k] = INFINITY; }

    for (int ch = 0; ch < nchunk; ++ch) {
        const int cbase = ch << 6;
        __syncthreads();   // previous chunk's sh_t readers are done

        // ---- build t-tile: t[e][cj] = relu(base[e] + ef[j].w1e[:,e]) ----
        {
            const int cj = t & 63, eg = t >> 6;
            const int jidx = cbase + cj;
            const int ok = (jidx < cnt);
            float e0 = 0.f, e1 = 0.f, e2 = 0.f;
            if (ok) {
                const int jj = sh_jlist[jidx];
                const float4 efv = *(const float4*)&sh_ef[jj * 4];
                e0 = efv.x; e1 = efv.y; e2 = efv.z;
            }
            #pragma unroll
            for (int v = 0; v < 16; ++v) {
                const int e = eg * 16 + v;
                float tv = 0.f;
                if (ok)
                    tv = fmaxf(fmaf(e0, sh_w1e[e],
                               fmaf(e1, sh_w1e[64 + e],
                               fmaf(e2, sh_w1e[128 + e], sh_base[e]))), 0.f);
                sh_t[e * 68 + cj] = tv;
            }
        }
        __syncthreads();

        // ---- gate GEMM: acc[4j][8d] += t[e][j] * W2[e][d] ----
        float acc[4][8];
        #pragma unroll
        for (int jj = 0; jj < 4; ++jj)
            #pragma unroll
            for (int k = 0; k < 8; ++k) acc[jj][k] = 0.f;

        #pragma unroll 2
        for (int e = 0; e < EE; ++e) {
            const float4 wa = *(const float4*)&su.W2[e * DD + dg * 8];
            const float4 wb = *(const float4*)&su.W2[e * DD + dg * 8 + 4];
            const float4 tv = *(const float4*)&sh_t[e * 68 + jg * 4];
            acc[0][0]=fmaf(tv.x,wa.x,acc[0][0]); acc[0][1]=fmaf(tv.x,wa.y,acc[0][1]);
            acc[0][2]=fmaf(tv.x,wa.z,acc[0][2]); acc[0][3]=fmaf(tv.x,wa.w,acc[0][3]);
            acc[0][4]=fmaf(tv.x,wb.x,acc[0][4]); acc[0][5]=fmaf(tv.x,wb.y,acc[0][5]);
            acc[0][6]=fmaf(tv.x,wb.z,acc[0][6]); acc[0][7]=fmaf(tv.x,wb.w,acc[0][7]);
            acc[1][0]=fmaf(tv.y,wa.x,acc[1][0]); acc[1][1]=fmaf(tv.y,wa.y,acc[1][1]);
            acc[1][2]=fmaf(tv.y,wa.z,acc[1][2]); acc[1][3]=fmaf(tv.y,wa.w,acc[1][3]);
            acc[1][4]=fmaf(tv.y,wb.x,acc[1][4]); acc[1][5]=fmaf(tv.y,wb.y,acc[1][5]);
            acc[1][6]=fmaf(tv.y,wb.z,acc[1][6]); acc[1][7]=fmaf(tv.y,wb.w,acc[1][7]);
            acc[2][0]=fmaf(tv.z,wa.x,acc[2][0]); acc[2][1]=fmaf(tv.z,wa.y,acc[2][1]);
            acc[2][2]=fmaf(tv.z,wa.z,acc[2][2]); acc[2][3]=fmaf(tv.z,wa.w,acc[2][3]);
            acc[2][4]=fmaf(tv.z,wb.x,acc[2][4]); acc[2][5]=fmaf(tv.z,wb.y,acc[2][5]);
            acc[2][6]=fmaf(tv.z,wb.z,acc[2][6]); acc[2][7]=fmaf(tv.z,wb.w,acc[2][7]);
            acc[3][0]=fmaf(tv.w,wa.x,acc[3][0]); acc[3][1]=fmaf(tv.w,wa.y,acc[3][1]);
            acc[3][2]=fmaf(tv.w,wa.z,acc[3][2]); acc[3][3]=fmaf(tv.w,wa.w,acc[3][3]);
            acc[3][4]=fmaf(tv.w,wb.x,acc[3][4]); acc[3][5]=fmaf(tv.w,wb.y,acc[3][5]);
            acc[3][6]=fmaf(tv.w,wb.z,acc[3][6]); acc[3][7]=fmaf(tv.w,wb.w,acc[3][7]);
        }

        // ---- sigmoid + per-thread running stats over valid j ----
        #pragma unroll
        for (int jj = 0; jj < 4; ++jj) {
            if (cbase + jg * 4 + jj < cnt) {
                #pragma unroll
                for (int k = 0; k < 8; ++k) {
                    const float g = 1.f / (1.f + __expf(-(acc[jj][k] + b2r[k])));
                    sumv[k] += g;
                    maxv[k]  = fmaxf(maxv[k], g);
                    minv[k]  = fminf(minv[k], g);
                }
            }
        }
    }

    __syncthreads();   // su.W2 dead; reuse as reduction scratch
    #pragma unroll
    for (int k = 0; k < 8; ++k) {
        su.red[0][jg * DD + dg * 8 + k] = sumv[k];
        su.red[1][jg * DD + dg * 8 + k] = maxv[k];
        su.red[2][jg * DD + dg * 8 + k] = minv[k];
    }
    __syncthreads();

    // ---- combine 16 j-groups; build upd_in = [h, agg_mean, agg_max] ----
    if (t < DD) {
        float s = 0.f, M = -INFINITY, mn = INFINITY;
        #pragma unroll 4
        for (int g = 0; g < 16; ++g) {
            s  += su.red[0][g * DD + t];
            M   = fmaxf(M,  su.red[1][g * DD + t]);
            mn  = fminf(mn, su.red[2][g * DD + t]);
        }
        const float hd  = sh_h[t];
        const float inv = 1.f / (float)(cnt > 0 ? cnt : 1);
        sh_upd[t]          = hd;
        sh_upd[DD + t]     = hd * s * inv;
        sh_upd[2 * DD + t] = (cnt > 0) ? ((hd >= 0.f) ? hd * M : hd * mn) : 0.f;
    }
    __syncthreads();

    // ---- update MLP: r = relu(upd_in @ U1 + b3) ----
    if (t < DD) {
        float r = b3_g[t];
        #pragma unroll 4
        for (int mm = 0; mm < 3 * DD; ++mm)
            r = fmaf(sh_upd[mm], U1_g[mm * DD + t], r);
        sh_r[t] = fmaxf(r, 0.f);
    }
    __syncthreads();

    // ---- o = r @ U2 + b4; x = h + o ----
    if (t < DD) {
        float o = b4_g[t];
        #pragma unroll 4
        for (int k2 = 0; k2 < DD; ++k2)
            o = fmaf(sh_r[k2], U2_g[k2 * DD + t], o);
        sh_x[t] = sh_h[t] + o;
    }
    __syncthreads();

    // ---- LayerNorm over D=128 ----
    if (t < DD) {
        float s = 0.f, s2 = 0.f;
        #pragma unroll 4
        for (int d = 0; d < DD; ++d) { const float v = sh_x[d]; s += v; s2 = fmaf(v, v, s2); }
        const float mu  = s * (1.f / 128.f);
        const float var = s2 * (1.f / 128.f) - mu * mu;
        const float rs  = rsqrtf(var + 1e-5f);
        const float y   = (sh_x[t] - mu) * rs * gam_g[t] + bet_g[t];
        out_g[bi * DD + t] = y;
    }
}

extern "C" void kernel_launch(void* const* d_in, const int* in_sizes, int n_in,
                              void* d_out, int out_size, void* d_ws, size_t ws_size,
                              hipStream_t stream) {
    ecgc_fused<<<BB * NN, 256, 0, stream>>>(
        (const float*)d_in[0],   // h
        (const float*)d_in[1],   // edge_feats
        (const int*)d_in[2],     // adj_mask
        (const float*)d_in[3],   // W1
        (const float*)d_in[4],   // b1
        (const float*)d_in[5],   // W2
        (const float*)d_in[6],   // b2
        (const float*)d_in[7],   // U1
        (const float*)d_in[8],   // b3
        (const float*)d_in[9],   // U2
        (const float*)d_in[10],  // b4
        (const float*)d_in[11],  // gamma
        (const float*)d_in[12],  // beta
        (float*)d_out);
}

// Round 3
// 197.570 us; speedup vs baseline: 1.4157x; 1.4157x over previous
//
#include <hip/hip_runtime.h>
#include <hip/hip_bf16.h>
#include <math.h>

#define BB 8
#define NN 256
#define DD 128
#define EE 64
#define TPAD 72   // padded row stride in ushorts for T / W2T (144 B = 36 dwords -> 2-way bank aliasing, free)

typedef __attribute__((ext_vector_type(8))) short short8;
typedef __attribute__((ext_vector_type(4))) float f32x4;

static __device__ __forceinline__ unsigned short f2bf(float f) {
    __hip_bfloat16 b = __float2bfloat16(f);
    return *reinterpret_cast<unsigned short*>(&b);
}

// One block per (b,i). 256 threads = 4 waves. LDS ~66 KB -> 2 blocks/CU.
__global__ __launch_bounds__(256, 2)
void ecgc_mfma(const float* __restrict__ h_g,
               const float* __restrict__ ef_g,
               const int*   __restrict__ mask_g,
               const float* __restrict__ W1_g,
               const float* __restrict__ b1_g,
               const float* __restrict__ W2_g,
               const float* __restrict__ b2_g,
               const float* __restrict__ U1_g,
               const float* __restrict__ b3_g,
               const float* __restrict__ U2_g,
               const float* __restrict__ b4_g,
               const float* __restrict__ gam_g,
               const float* __restrict__ bet_g,
               float*       __restrict__ out_g)
{
    const int bi   = blockIdx.x;      // b*N + i
    const int t    = threadIdx.x;     // 0..255
    const int lane = t & 63;
    const int w    = t >> 6;          // wave 0..3
    const int m16  = lane & 15;
    const int quad = lane >> 4;

    __shared__ __align__(16) unsigned short shT[NN * TPAD];     // 36.9 KB  T[j][e] bf16
    __shared__ __align__(16) unsigned short shW2T[DD * TPAD];   // 18.4 KB  W2T[d][e] bf16
    __shared__ __align__(16) float sh_ef[NN * 4];               // 4 KB
    __shared__ float sh_h[DD], sh_b2[DD], sh_base[EE], sh_w1e[3 * EE];
    __shared__ float sh_sum[DD], sh_mx[DD], sh_mn[DD];
    __shared__ float sh_upd[3 * DD], sh_r[DD], sh_x[DD], sh_part[2 * DD];
    __shared__ int   sh_jlist[NN], sh_wcnt[4], sh_cnt;

    // ---------------- stage ----------------
    if (t < DD) { sh_h[t] = h_g[bi * DD + t]; sh_b2[t] = b2_g[t]; }
    {   // edge-feature row, float4-padded
        const float* efr = ef_g + (size_t)bi * NN * 3;
        sh_ef[t * 4 + 0] = efr[t * 3 + 0];
        sh_ef[t * 4 + 1] = efr[t * 3 + 1];
        sh_ef[t * 4 + 2] = efr[t * 3 + 2];
        sh_ef[t * 4 + 3] = 0.f;
    }
    {   // W2T staging: thread owns (d = t&127, e in [eh*32, eh*32+32)); coalesced global dword reads,
        // b128 LDS writes at 2-way bank aliasing.
        const int d = t & 127, eh = t >> 7;
        for (int blk = 0; blk < 4; ++blk) {
            const int e0 = eh * 32 + blk * 8;
            unsigned short tmp[8];
            #pragma unroll
            for (int v = 0; v < 8; ++v)
                tmp[v] = f2bf(W2_g[(e0 + v) * DD + d]);
            *(short8*)&shW2T[d * TPAD + e0] = *(const short8*)tmp;
        }
    }

    // mask + ballot compaction
    const int mk = (mask_g[bi * NN + t] != 0) ? 1 : 0;
    {
        const unsigned long long bal = __ballot(mk);
        if (lane == 0) sh_wcnt[w] = __popcll(bal);
        const int pre = __popcll(bal & ((1ull << lane) - 1ull));
        __syncthreads();
        int wbase = 0;
        for (int ww = 0; ww < w; ++ww) wbase += sh_wcnt[ww];
        if (mk) sh_jlist[wbase + pre] = t;
        if (t == 0) sh_cnt = sh_wcnt[0] + sh_wcnt[1] + sh_wcnt[2] + sh_wcnt[3];
    }

    // base[e] = b1[e] + h . W1[:128,e];  w1e = W1[128:131,:]
    if (t < EE) {
        float acc = b1_g[t];
        #pragma unroll 4
        for (int d = 0; d < DD; ++d)
            acc = fmaf(sh_h[d], W1_g[d * EE + t], acc);
        sh_base[t] = acc;
    } else {
        const int u = t - EE;        // 0..191
        sh_w1e[u] = W1_g[(DD + (u >> 6)) * EE + (u & 63)];
    }
    __syncthreads();

    const int cnt = sh_cnt;
    const int njt = (cnt + 15) >> 4;

    // ---------------- build T (bf16, compacted j rows; invalid rows zeroed) ----------------
    {
        const int cj = t & 63, eg = w;    // eg*16 .. eg*16+15 e-range
        for (int c = 0; c < 4; ++c) {
            const int js = c * 64 + cj;
            float e0 = 0.f, e1 = 0.f, e2 = 0.f;
            const int ok = (js < cnt);
            if (ok) {
                const float4 efv = *(const float4*)&sh_ef[sh_jlist[js] * 4];
                e0 = efv.x; e1 = efv.y; e2 = efv.z;
            }
            unsigned short pk[16];
            #pragma unroll
            for (int v = 0; v < 16; ++v) {
                const int e = eg * 16 + v;
                float tv = 0.f;
                if (ok)
                    tv = fmaxf(fmaf(e0, sh_w1e[e],
                               fmaf(e1, sh_w1e[64 + e],
                               fmaf(e2, sh_w1e[128 + e], sh_base[e]))), 0.f);
                pk[v] = f2bf(tv);
            }
            *(short8*)&shT[js * TPAD + eg * 16]     = *(const short8*)&pk[0];
            *(short8*)&shT[js * TPAD + eg * 16 + 8] = *(const short8*)&pk[8];
        }
    }
    __syncthreads();

    // ---------------- MFMA gate GEMM + fused sigmoid/stats ----------------
    // wave w owns d-stripe [32w, 32w+32): 2 d-tiles of 16.
    const int dstripe = w * 32;
    float sumv[2] = {0.f, 0.f};
    float mxv[2]  = {-__builtin_inff(), -__builtin_inff()};
    float mnv[2]  = { __builtin_inff(),  __builtin_inff()};

    short8 bfrag[2][2];
    float  nb2[2];
    #pragma unroll
    for (int dt = 0; dt < 2; ++dt) {
        const int d = dstripe + 16 * dt + m16;
        nb2[dt] = sh_b2[d];
        #pragma unroll
        for (int kh = 0; kh < 2; ++kh)
            bfrag[dt][kh] = *(const short8*)&shW2T[d * TPAD + kh * 32 + quad * 8];
    }

    for (int jt = 0; jt < njt; ++jt) {
        const short8 a0 = *(const short8*)&shT[(jt * 16 + m16) * TPAD + quad * 8];
        const short8 a1 = *(const short8*)&shT[(jt * 16 + m16) * TPAD + 32 + quad * 8];
        const int jbase = jt * 16 + quad * 4;
        #pragma unroll
        for (int dt = 0; dt < 2; ++dt) {
            f32x4 acc = {0.f, 0.f, 0.f, 0.f};
            acc = __builtin_amdgcn_mfma_f32_16x16x32_bf16(a0, bfrag[dt][0], acc, 0, 0, 0);
            acc = __builtin_amdgcn_mfma_f32_16x16x32_bf16(a1, bfrag[dt][1], acc, 0, 0, 0);
            #pragma unroll
            for (int r = 0; r < 4; ++r) {
                const float g = __fdividef(1.f, 1.f + __expf(-(acc[r] + nb2[dt])));
                if (jbase + r < cnt) {
                    sumv[dt] += g;
                    mxv[dt]  = fmaxf(mxv[dt], g);
                    mnv[dt]  = fminf(mnv[dt], g);
                }
            }
        }
    }

    // cross-quad reduce (rows live in quads), then lane<16 writes per-d stats
    #pragma unroll
    for (int dt = 0; dt < 2; ++dt) {
        float s = sumv[dt], M = mxv[dt], mn = mnv[dt];
        s += __shfl_xor(s, 16, 64);  s += __shfl_xor(s, 32, 64);
        M  = fmaxf(M,  __shfl_xor(M, 16, 64));  M  = fmaxf(M,  __shfl_xor(M, 32, 64));
        mn = fminf(mn, __shfl_xor(mn, 16, 64)); mn = fminf(mn, __shfl_xor(mn, 32, 64));
        if (quad == 0) {
            const int d = dstripe + 16 * dt + m16;
            sh_sum[d] = s; sh_mx[d] = M; sh_mn[d] = mn;
        }
    }
    __syncthreads();

    // ---------------- combine: upd_in = [h, agg_mean, agg_max] ----------------
    if (t < DD) {
        const float hd = sh_h[t];
        float mean = 0.f, amax = 0.f;
        if (cnt > 0) {
            mean = hd * sh_sum[t] * __fdividef(1.f, (float)cnt);
            amax = (hd >= 0.f) ? hd * sh_mx[t] : hd * sh_mn[t];
        }
        sh_upd[t] = hd; sh_upd[DD + t] = mean; sh_upd[2 * DD + t] = amax;
    }
    __syncthreads();

    // ---------------- update MLP, K-split across both thread-halves ----------------
    {
        const int d = t & 127, half = t >> 7;
        const int k0 = half * 192;
        float p = 0.f;
        #pragma unroll 4
        for (int mm = 0; mm < 192; ++mm)
            p = fmaf(sh_upd[k0 + mm], U1_g[(k0 + mm) * DD + d], p);
        sh_part[half * DD + d] = p;
    }
    __syncthreads();
    if (t < DD) sh_r[t] = fmaxf(sh_part[t] + sh_part[DD + t] + b3_g[t], 0.f);
    __syncthreads();
    {
        const int d = t & 127, half = t >> 7;
        float p = 0.f;
        #pragma unroll 4
        for (int k = 0; k < 64; ++k)
            p = fmaf(sh_r[half * 64 + k], U2_g[(half * 64 + k) * DD + d], p);
        sh_part[half * DD + d] = p;
    }
    __syncthreads();
    if (t < DD) sh_x[t] = sh_h[t] + sh_part[t] + sh_part[DD + t] + b4_g[t];
    __syncthreads();

    // ---------------- LayerNorm over D=128 ----------------
    if (t < DD) {
        float s = 0.f, s2 = 0.f;
        #pragma unroll 4
        for (int d = 0; d < DD; ++d) { const float v = sh_x[d]; s += v; s2 = fmaf(v, v, s2); }
        const float mu  = s * (1.f / 128.f);
        const float var = s2 * (1.f / 128.f) - mu * mu;
        const float rs  = rsqrtf(var + 1e-5f);
        out_g[bi * DD + t] = (sh_x[t] - mu) * rs * gam_g[t] + bet_g[t];
    }
}

extern "C" void kernel_launch(void* const* d_in, const int* in_sizes, int n_in,
                              void* d_out, int out_size, void* d_ws, size_t ws_size,
                              hipStream_t stream) {
    ecgc_mfma<<<BB * NN, 256, 0, stream>>>(
        (const float*)d_in[0],   // h
        (const float*)d_in[1],   // edge_feats
        (const int*)d_in[2],     // adj_mask
        (const float*)d_in[3],   // W1
        (const float*)d_in[4],   // b1
        (const float*)d_in[5],   // W2
        (const float*)d_in[6],   // b2
        (const float*)d_in[7],   // U1
        (const float*)d_in[8],   // b3
        (const float*)d_in[9],   // U2
        (const float*)d_in[10],  // b4
        (const float*)d_in[11],  // gamma
        (const float*)d_in[12],  // beta
        (float*)d_out);
}

// Round 4
// 140.058 us; speedup vs baseline: 1.9970x; 1.4106x over previous
//
#include <hip/hip_runtime.h>
#include <hip/hip_bf16.h>
#include <math.h>

#define NN 256
#define DD 128
#define EE 64
#define TPAD 72    // shT row stride (ushorts): 144 B -> 2-way bank aliasing (free)
#define APAD 392   // kernel2 A row stride (ushorts): 384+8
#define RPAD 136   // kernel2 rbuf row stride (ushorts): 128+8

typedef __attribute__((ext_vector_type(8))) short short8;
typedef __attribute__((ext_vector_type(4))) float f32x4;

static __device__ __forceinline__ unsigned short f2bf(float f) {
    __hip_bfloat16 b = __float2bfloat16(f);
    return *reinterpret_cast<unsigned short*>(&b);
}

// Build a bf16 B-fragment for mfma_16x16x32: rows k=kbase..kbase+7, col d, from
// row-major f32 B[K][128] in global (L1/L2-resident weights).
static __device__ __forceinline__ short8 ldb(const float* __restrict__ B, int kbase, int d) {
    unsigned short tmp[8];
    #pragma unroll
    for (int j = 0; j < 8; ++j) tmp[j] = f2bf(B[(kbase + j) * DD + d]);
    return *(const short8*)tmp;
}

// ---------------- Kernel 1: gate + masked aggregation ----------------
// One block per (b,i). LDS ~44 KB -> 3 blocks/CU.
// ws[bi*256 + d]       = agg_mean[d]  (= h_d * sum(g)/cnt)
// ws[bi*256 + 128 + d] = agg_max[d]
__global__ __launch_bounds__(256, 3)
void ecgc_gate(const float* __restrict__ h_g,
               const float* __restrict__ ef_g,
               const int*   __restrict__ mask_g,
               const float* __restrict__ W1_g,
               const float* __restrict__ b1_g,
               const float* __restrict__ W2_g,
               const float* __restrict__ b2_g,
               float*       __restrict__ ws)
{
    const int bi   = blockIdx.x;
    const int t    = threadIdx.x;
    const int lane = t & 63;
    const int w    = t >> 6;
    const int m16  = lane & 15;
    const int quad = lane >> 4;

    __shared__ __align__(16) unsigned short shT[NN * TPAD];   // 36.9 KB
    __shared__ __align__(16) float sh_ef[NN * 4];             // 4 KB
    __shared__ float sh_h[DD], sh_base[EE], sh_w1e[3 * EE];
    __shared__ int   sh_jlist[NN], sh_wcnt[4], sh_cnt;

    if (t < DD) sh_h[t] = h_g[bi * DD + t];
    {   // edge-feature row, float4-padded
        const float* efr = ef_g + (size_t)bi * NN * 3;
        sh_ef[t * 4 + 0] = efr[t * 3 + 0];
        sh_ef[t * 4 + 1] = efr[t * 3 + 1];
        sh_ef[t * 4 + 2] = efr[t * 3 + 2];
        sh_ef[t * 4 + 3] = 0.f;
    }
    const int mk = (mask_g[bi * NN + t] != 0) ? 1 : 0;
    const unsigned long long bal = __ballot(mk);
    if (lane == 0) sh_wcnt[w] = __popcll(bal);
    const int pre = __popcll(bal & ((1ull << lane) - 1ull));
    __syncthreads();

    {
        int wbase = 0;
        for (int ww = 0; ww < w; ++ww) wbase += sh_wcnt[ww];
        if (mk) sh_jlist[wbase + pre] = t;
        if (t == 0) sh_cnt = sh_wcnt[0] + sh_wcnt[1] + sh_wcnt[2] + sh_wcnt[3];
    }

    // base[e] = b1[e] + h . W1[:128,e];  w1e = W1[128:131,:]
    if (t < EE) {
        float acc = b1_g[t];
        #pragma unroll 4
        for (int d = 0; d < DD; ++d)
            acc = fmaf(sh_h[d], W1_g[d * EE + t], acc);
        sh_base[t] = acc;
    } else {
        const int u = t - EE;
        sh_w1e[u] = W1_g[(DD + (u >> 6)) * EE + (u & 63)];
    }

    // W2 B-fragments straight from global (L1-resident, shared by all blocks);
    // latency overlaps T-build below.
    const int dstripe = w * 32;
    short8 bfrag[2][2];
    float  nb2[2];
    #pragma unroll
    for (int dt = 0; dt < 2; ++dt) {
        const int d = dstripe + 16 * dt + m16;
        nb2[dt] = b2_g[d];
        #pragma unroll
        for (int kh = 0; kh < 2; ++kh)
            bfrag[dt][kh] = ldb(W2_g, kh * 32 + quad * 8, d);
    }
    __syncthreads();

    const int cnt = sh_cnt;
    const int njt = (cnt + 15) >> 4;

    // build T (bf16, compacted j rows; invalid rows zeroed)
    {
        const int cj = t & 63, eg = w;
        for (int c = 0; c < 4; ++c) {
            const int js = c * 64 + cj;
            float e0 = 0.f, e1 = 0.f, e2 = 0.f;
            const int ok = (js < cnt);
            if (ok) {
                const float4 efv = *(const float4*)&sh_ef[sh_jlist[js] * 4];
                e0 = efv.x; e1 = efv.y; e2 = efv.z;
            }
            unsigned short pk[16];
            #pragma unroll
            for (int v = 0; v < 16; ++v) {
                const int e = eg * 16 + v;
                float tv = 0.f;
                if (ok)
                    tv = fmaxf(fmaf(e0, sh_w1e[e],
                               fmaf(e1, sh_w1e[64 + e],
                               fmaf(e2, sh_w1e[128 + e], sh_base[e]))), 0.f);
                pk[v] = f2bf(tv);
            }
            *(short8*)&shT[js * TPAD + eg * 16]     = *(const short8*)&pk[0];
            *(short8*)&shT[js * TPAD + eg * 16 + 8] = *(const short8*)&pk[8];
        }
    }
    __syncthreads();

    // MFMA gate GEMM + fused sigmoid / stats
    float sumv[2] = {0.f, 0.f};
    float mxv[2]  = {-__builtin_inff(), -__builtin_inff()};
    float mnv[2]  = { __builtin_inff(),  __builtin_inff()};

    for (int jt = 0; jt < njt; ++jt) {
        const short8 a0 = *(const short8*)&shT[(jt * 16 + m16) * TPAD + quad * 8];
        const short8 a1 = *(const short8*)&shT[(jt * 16 + m16) * TPAD + 32 + quad * 8];
        const int jbase = jt * 16 + quad * 4;
        #pragma unroll
        for (int dt = 0; dt < 2; ++dt) {
            f32x4 acc = {0.f, 0.f, 0.f, 0.f};
            acc = __builtin_amdgcn_mfma_f32_16x16x32_bf16(a0, bfrag[dt][0], acc, 0, 0, 0);
            acc = __builtin_amdgcn_mfma_f32_16x16x32_bf16(a1, bfrag[dt][1], acc, 0, 0, 0);
            #pragma unroll
            for (int r = 0; r < 4; ++r) {
                const float g = __fdividef(1.f, 1.f + __expf(-(acc[r] + nb2[dt])));
                if (jbase + r < cnt) {
                    sumv[dt] += g;
                    mxv[dt]  = fmaxf(mxv[dt], g);
                    mnv[dt]  = fminf(mnv[dt], g);
                }
            }
        }
    }

    #pragma unroll
    for (int dt = 0; dt < 2; ++dt) {
        float s = sumv[dt], M = mxv[dt], mn = mnv[dt];
        s += __shfl_xor(s, 16, 64);  s += __shfl_xor(s, 32, 64);
        M  = fmaxf(M,  __shfl_xor(M, 16, 64));  M  = fmaxf(M,  __shfl_xor(M, 32, 64));
        mn = fminf(mn, __shfl_xor(mn, 16, 64)); mn = fminf(mn, __shfl_xor(mn, 32, 64));
        if (quad == 0) {
            const int d  = dstripe + 16 * dt + m16;
            const float hd = sh_h[d];
            float mean = 0.f, amax = 0.f;
            if (cnt > 0) {
                mean = hd * s * __fdividef(1.f, (float)cnt);
                amax = (hd >= 0.f) ? hd * M : hd * mn;
            }
            ws[bi * 256 + d]       = mean;
            ws[bi * 256 + 128 + d] = amax;
        }
    }
}

// ---------------- Kernel 2: batched update MLP + LayerNorm ----------------
// 32 rows/block, 64 blocks. upd_in = [h | ws_mean | ws_max] (K=384).
__global__ __launch_bounds__(256, 2)
void ecgc_upd(const float* __restrict__ h_g,
              const float* __restrict__ ws,
              const float* __restrict__ U1_g,
              const float* __restrict__ b3_g,
              const float* __restrict__ U2_g,
              const float* __restrict__ b4_g,
              const float* __restrict__ gam_g,
              const float* __restrict__ bet_g,
              float*       __restrict__ out_g)
{
    const int bi0  = blockIdx.x * 32;
    const int t    = threadIdx.x;
    const int lane = t & 63;
    const int w    = t >> 6;
    const int m16  = lane & 15;
    const int quad = lane >> 4;

    __shared__ __align__(16) unsigned short shA[32 * APAD];    // 25.1 KB bf16 upd_in
    __shared__ __align__(16) unsigned short rbuf[32 * RPAD];   // 8.7 KB bf16 relu-hidden
    __shared__ float sh_s[4 * 32], sh_s2[4 * 32], sh_mu[32], sh_rs[32];

    // ---- stage A-tile (row = t>>3, 8 threads/row, 16 cols per segment each) ----
    {
        const int row = t >> 3, q = t & 7;
        const float* srcs[3] = { h_g + (size_t)(bi0 + row) * DD + q * 16,
                                 ws  + (size_t)(bi0 + row) * 256 + q * 16,
                                 ws  + (size_t)(bi0 + row) * 256 + 128 + q * 16 };
        #pragma unroll
        for (int seg = 0; seg < 3; ++seg) {
            const float4* sp = (const float4*)srcs[seg];
            unsigned short tmp[16];
            #pragma unroll
            for (int vv = 0; vv < 4; ++vv) {
                const float4 v = sp[vv];
                tmp[vv * 4 + 0] = f2bf(v.x); tmp[vv * 4 + 1] = f2bf(v.y);
                tmp[vv * 4 + 2] = f2bf(v.z); tmp[vv * 4 + 3] = f2bf(v.w);
            }
            *(short8*)&shA[row * APAD + seg * DD + q * 16]     = *(const short8*)&tmp[0];
            *(short8*)&shA[row * APAD + seg * DD + q * 16 + 8] = *(const short8*)&tmp[8];
        }
    }
    __syncthreads();

    const int dstripe = w * 32;

    // ---- GEMM1: (32 x 384) @ (384 x 128), wave owns 32-col d-stripe ----
    f32x4 acc[2][2];
    #pragma unroll
    for (int mt = 0; mt < 2; ++mt)
        #pragma unroll
        for (int dt = 0; dt < 2; ++dt) acc[mt][dt] = (f32x4){0.f, 0.f, 0.f, 0.f};

    for (int kk = 0; kk < 12; ++kk) {
        const short8 a0 = *(const short8*)&shA[m16 * APAD + kk * 32 + quad * 8];
        const short8 a1 = *(const short8*)&shA[(16 + m16) * APAD + kk * 32 + quad * 8];
        #pragma unroll
        for (int dt = 0; dt < 2; ++dt) {
            const short8 b = ldb(U1_g, kk * 32 + quad * 8, dstripe + dt * 16 + m16);
            acc[0][dt] = __builtin_amdgcn_mfma_f32_16x16x32_bf16(a0, b, acc[0][dt], 0, 0, 0);
            acc[1][dt] = __builtin_amdgcn_mfma_f32_16x16x32_bf16(a1, b, acc[1][dt], 0, 0, 0);
        }
    }

    // ---- relu + b3, transpose C->A layout through LDS ----
    #pragma unroll
    for (int mt = 0; mt < 2; ++mt)
        #pragma unroll
        for (int dt = 0; dt < 2; ++dt) {
            const int d = dstripe + dt * 16 + m16;
            const float bb = b3_g[d];
            #pragma unroll
            for (int r = 0; r < 4; ++r) {
                const int ro = mt * 16 + quad * 4 + r;
                rbuf[ro * RPAD + d] = f2bf(fmaxf(acc[mt][dt][r] + bb, 0.f));
            }
        }
    __syncthreads();

    // ---- GEMM2: (32 x 128) @ (128 x 128) ----
    f32x4 acc2[2][2];
    #pragma unroll
    for (int mt = 0; mt < 2; ++mt)
        #pragma unroll
        for (int dt = 0; dt < 2; ++dt) acc2[mt][dt] = (f32x4){0.f, 0.f, 0.f, 0.f};

    for (int kk = 0; kk < 4; ++kk) {
        const short8 a0 = *(const short8*)&rbuf[m16 * RPAD + kk * 32 + quad * 8];
        const short8 a1 = *(const short8*)&rbuf[(16 + m16) * RPAD + kk * 32 + quad * 8];
        #pragma unroll
        for (int dt = 0; dt < 2; ++dt) {
            const short8 b = ldb(U2_g, kk * 32 + quad * 8, dstripe + dt * 16 + m16);
            acc2[0][dt] = __builtin_amdgcn_mfma_f32_16x16x32_bf16(a0, b, acc2[0][dt], 0, 0, 0);
            acc2[1][dt] = __builtin_amdgcn_mfma_f32_16x16x32_bf16(a1, b, acc2[1][dt], 0, 0, 0);
        }
    }

    // ---- x = h + upd + b4 (h re-read fp32 for precision) ----
    float xv[2][2][4];
    #pragma unroll
    for (int mt = 0; mt < 2; ++mt)
        #pragma unroll
        for (int dt = 0; dt < 2; ++dt) {
            const int d = dstripe + dt * 16 + m16;
            const float bb = b4_g[d];
            #pragma unroll
            for (int r = 0; r < 4; ++r) {
                const int ro = mt * 16 + quad * 4 + r;
                xv[mt][dt][r] = h_g[(size_t)(bi0 + ro) * DD + d] + acc2[mt][dt][r] + bb;
            }
        }

    // ---- LN: per-row mean/var; wave covers its 32-col stripe, combine via LDS ----
    #pragma unroll
    for (int mt = 0; mt < 2; ++mt)
        #pragma unroll
        for (int r = 0; r < 4; ++r) {
            float s  = xv[mt][0][r] + xv[mt][1][r];
            float s2 = xv[mt][0][r] * xv[mt][0][r] + xv[mt][1][r] * xv[mt][1][r];
            #pragma unroll
            for (int off = 1; off < 16; off <<= 1) {
                s  += __shfl_xor(s,  off, 64);
                s2 += __shfl_xor(s2, off, 64);
            }
            if (m16 == 0) {
                const int ro = mt * 16 + quad * 4 + r;
                sh_s[w * 32 + ro]  = s;
                sh_s2[w * 32 + ro] = s2;
            }
        }
    __syncthreads();
    if (t < 32) {
        const float S  = sh_s[t]  + sh_s[32 + t]  + sh_s[64 + t]  + sh_s[96 + t];
        const float S2 = sh_s2[t] + sh_s2[32 + t] + sh_s2[64 + t] + sh_s2[96 + t];
        const float mu  = S * (1.f / 128.f);
        const float var = S2 * (1.f / 128.f) - mu * mu;
        sh_mu[t] = mu;
        sh_rs[t] = rsqrtf(var + 1e-5f);
    }
    __syncthreads();

    #pragma unroll
    for (int mt = 0; mt < 2; ++mt)
        #pragma unroll
        for (int dt = 0; dt < 2; ++dt) {
            const int d = dstripe + dt * 16 + m16;
            const float ga = gam_g[d], be = bet_g[d];
            #pragma unroll
            for (int r = 0; r < 4; ++r) {
                const int ro = mt * 16 + quad * 4 + r;
                out_g[(size_t)(bi0 + ro) * DD + d] =
                    (xv[mt][dt][r] - sh_mu[ro]) * sh_rs[ro] * ga + be;
            }
        }
}

extern "C" void kernel_launch(void* const* d_in, const int* in_sizes, int n_in,
                              void* d_out, int out_size, void* d_ws, size_t ws_size,
                              hipStream_t stream) {
    float* ws = (float*)d_ws;   // 2048 * 256 floats = 2 MB
    ecgc_gate<<<8 * NN, 256, 0, stream>>>(
        (const float*)d_in[0],   // h
        (const float*)d_in[1],   // edge_feats
        (const int*)d_in[2],     // adj_mask
        (const float*)d_in[3],   // W1
        (const float*)d_in[4],   // b1
        (const float*)d_in[5],   // W2
        (const float*)d_in[6],   // b2
        ws);
    ecgc_upd<<<(8 * NN) / 32, 256, 0, stream>>>(
        (const float*)d_in[0],   // h
        ws,
        (const float*)d_in[7],   // U1
        (const float*)d_in[8],   // b3
        (const float*)d_in[9],   // U2
        (const float*)d_in[10],  // b4
        (const float*)d_in[11],  // gamma
        (const float*)d_in[12],  // beta
        (float*)d_out);
}

// Round 5
// 125.473 us; speedup vs baseline: 2.2291x; 1.1162x over previous
//
#include <hip/hip_runtime.h>
#include <hip/hip_bf16.h>
#include <math.h>

#define NN 256
#define DD 128
#define EE 64
#define TPAD 72    // shT row stride (ushorts): 144 B -> 2-way bank aliasing (free)
#define APAD 392   // kernel2 A row stride (ushorts): 384+8
#define RPAD 136   // kernel2 rbuf row stride (ushorts): 128+8

typedef __attribute__((ext_vector_type(8))) short short8;
typedef __attribute__((ext_vector_type(4))) float f32x4;

static __device__ __forceinline__ unsigned short f2bf(float f) {
    __hip_bfloat16 b = __float2bfloat16(f);
    return *reinterpret_cast<unsigned short*>(&b);
}

// bf16 B-fragment for mfma_16x16x32 from row-major f32 B[K][128] in global.
static __device__ __forceinline__ short8 ldb(const float* __restrict__ B, int kbase, int d) {
    unsigned short tmp[8];
    #pragma unroll
    for (int j = 0; j < 8; ++j) tmp[j] = f2bf(B[(kbase + j) * DD + d]);
    return *(const short8*)tmp;
}

// ---------------- Kernel 1: gate + masked aggregation ----------------
// One block per (b,i). LDS ~17 KB -> ~6 blocks/CU (VGPR-capped).
// ws[bi*256 + d] = agg_mean[d];  ws[bi*256 + 128 + d] = agg_max[d]
__global__ __launch_bounds__(256, 6)
void ecgc_gate(const float* __restrict__ h_g,
               const float* __restrict__ ef_g,
               const int*   __restrict__ mask_g,
               const float* __restrict__ W1_g,
               const float* __restrict__ b1_g,
               const float* __restrict__ W2_g,
               const float* __restrict__ b2_g,
               float*       __restrict__ ws)
{
    const int bi   = blockIdx.x;
    const int t    = threadIdx.x;
    const int lane = t & 63;
    const int w    = t >> 6;
    const int m16  = lane & 15;
    const int quad = lane >> 4;

    __shared__ __align__(16) unsigned short shT[64 * TPAD];  // 9.2 KB (one 64-row chunk)
    __shared__ __align__(16) float sh_ef[NN * 4];            // 4 KB
    __shared__ __align__(16) float sh_base[EE];
    __shared__ __align__(16) float sh_w1e[3 * EE];
    __shared__ float sh_h[DD];
    __shared__ float sh_basep[4 * EE];
    __shared__ int   sh_jlist[NN], sh_wcnt[4], sh_cnt;

    // ---- stage (no LDS interdependence yet) ----
    if (t < DD) sh_h[t] = h_g[bi * DD + t];
    if (t < 192) sh_w1e[t] = W1_g[(DD + (t >> 6)) * EE + (t & 63)];
    {
        const float* efr = ef_g + (size_t)bi * NN * 3;
        sh_ef[t * 4 + 0] = efr[t * 3 + 0];
        sh_ef[t * 4 + 1] = efr[t * 3 + 1];
        sh_ef[t * 4 + 2] = efr[t * 3 + 2];
        sh_ef[t * 4 + 3] = 0.f;
    }
    const int mk = (mask_g[bi * NN + t] != 0) ? 1 : 0;
    const unsigned long long bal = __ballot(mk);
    if (lane == 0) sh_wcnt[w] = __popcll(bal);
    const int pre = __popcll(bal & ((1ull << lane) - 1ull));

    // W2 B-fragments from global (L1-resident); latency overlaps staging.
    const int dstripe = w * 32;
    short8 bfrag[2][2];
    float  nb2[2];
    #pragma unroll
    for (int dt = 0; dt < 2; ++dt) {
        const int d = dstripe + 16 * dt + m16;
        nb2[dt] = b2_g[d];
        #pragma unroll
        for (int kh = 0; kh < 2; ++kh)
            bfrag[dt][kh] = ldb(W2_g, kh * 32 + quad * 8, d);
    }
    __syncthreads();

    // ---- jlist scatter + base partials (all 256 threads) ----
    {
        int wbase = 0;
        for (int ww = 0; ww < w; ++ww) wbase += sh_wcnt[ww];
        if (mk) sh_jlist[wbase + pre] = t;
        if (t == 0) sh_cnt = sh_wcnt[0] + sh_wcnt[1] + sh_wcnt[2] + sh_wcnt[3];
    }
    {   // thread (e = t&63, dgrp = t>>6): partial over 32 d's; coalesced W1 reads
        const int e = t & 63, dgrp = t >> 6;
        float acc = 0.f;
        #pragma unroll 4
        for (int d = dgrp * 32; d < dgrp * 32 + 32; ++d)
            acc = fmaf(sh_h[d], W1_g[d * EE + e], acc);
        sh_basep[dgrp * EE + e] = acc;
    }
    __syncthreads();
    if (t < EE)
        sh_base[t] = b1_g[t] + sh_basep[t] + sh_basep[EE + t] +
                     sh_basep[2 * EE + t] + sh_basep[3 * EE + t];
    __syncthreads();

    const int cnt = sh_cnt;
    const int nch = (cnt + 63) >> 6;

    float sumv[2] = {0.f, 0.f};
    float mxv[2]  = {-__builtin_inff(), -__builtin_inff()};
    float mnv[2]  = { __builtin_inff(),  __builtin_inff()};

    for (int ch = 0; ch < nch; ++ch) {
        // ---- build one 64-row chunk of T: thread -> row t>>2, e-range (t&3)*16 ----
        {
            const int row = t >> 2, e0 = (t & 3) * 16;
            const int js  = ch * 64 + row;
            const int ok  = (js < cnt);
            float e0f = 0.f, e1f = 0.f, e2f = 0.f;
            if (ok) {
                const float4 efv = *(const float4*)&sh_ef[sh_jlist[js] * 4];
                e0f = efv.x; e1f = efv.y; e2f = efv.z;
            }
            unsigned short pk[16];
            #pragma unroll
            for (int vb = 0; vb < 4; ++vb) {
                const float4 bs = *(const float4*)&sh_base[e0 + vb * 4];
                const float4 w0 = *(const float4*)&sh_w1e[e0 + vb * 4];
                const float4 w1 = *(const float4*)&sh_w1e[64 + e0 + vb * 4];
                const float4 w2 = *(const float4*)&sh_w1e[128 + e0 + vb * 4];
                const float bsx[4] = {bs.x, bs.y, bs.z, bs.w};
                const float w0x[4] = {w0.x, w0.y, w0.z, w0.w};
                const float w1x[4] = {w1.x, w1.y, w1.z, w1.w};
                const float w2x[4] = {w2.x, w2.y, w2.z, w2.w};
                #pragma unroll
                for (int v = 0; v < 4; ++v) {
                    float tv = 0.f;
                    if (ok)
                        tv = fmaxf(fmaf(e0f, w0x[v],
                                   fmaf(e1f, w1x[v],
                                   fmaf(e2f, w2x[v], bsx[v]))), 0.f);
                    pk[vb * 4 + v] = f2bf(tv);
                }
            }
            *(short8*)&shT[row * TPAD + e0]     = *(const short8*)&pk[0];
            *(short8*)&shT[row * TPAD + e0 + 8] = *(const short8*)&pk[8];
        }
        __syncthreads();

        // ---- MFMA over this chunk's j-tiles + fused sigmoid/stats ----
        const int rem = min(64, cnt - ch * 64);
        const int jtn = (rem + 15) >> 4;
        for (int jt = 0; jt < jtn; ++jt) {
            const short8 a0 = *(const short8*)&shT[(jt * 16 + m16) * TPAD + quad * 8];
            const short8 a1 = *(const short8*)&shT[(jt * 16 + m16) * TPAD + 32 + quad * 8];
            const int jbase = ch * 64 + jt * 16 + quad * 4;
            #pragma unroll
            for (int dt = 0; dt < 2; ++dt) {
                f32x4 acc = {0.f, 0.f, 0.f, 0.f};
                acc = __builtin_amdgcn_mfma_f32_16x16x32_bf16(a0, bfrag[dt][0], acc, 0, 0, 0);
                acc = __builtin_amdgcn_mfma_f32_16x16x32_bf16(a1, bfrag[dt][1], acc, 0, 0, 0);
                #pragma unroll
                for (int r = 0; r < 4; ++r) {
                    const float g = __fdividef(1.f, 1.f + __expf(-(acc[r] + nb2[dt])));
                    if (jbase + r < cnt) {
                        sumv[dt] += g;
                        mxv[dt]  = fmaxf(mxv[dt], g);
                        mnv[dt]  = fminf(mnv[dt], g);
                    }
                }
            }
        }
        __syncthreads();   // before next chunk overwrites shT
    }

    // ---- cross-quad reduce, aggregate, write ws ----
    #pragma unroll
    for (int dt = 0; dt < 2; ++dt) {
        float s = sumv[dt], M = mxv[dt], mn = mnv[dt];
        s += __shfl_xor(s, 16, 64);  s += __shfl_xor(s, 32, 64);
        M  = fmaxf(M,  __shfl_xor(M, 16, 64));  M  = fmaxf(M,  __shfl_xor(M, 32, 64));
        mn = fminf(mn, __shfl_xor(mn, 16, 64)); mn = fminf(mn, __shfl_xor(mn, 32, 64));
        if (quad == 0) {
            const int d  = dstripe + 16 * dt + m16;
            const float hd = sh_h[d];
            float mean = 0.f, amax = 0.f;
            if (cnt > 0) {
                mean = hd * s * __fdividef(1.f, (float)cnt);
                amax = (hd >= 0.f) ? hd * M : hd * mn;
            }
            ws[bi * 256 + d]       = mean;
            ws[bi * 256 + 128 + d] = amax;
        }
    }
}

// ---------------- Kernel 2: batched update MLP + LayerNorm ----------------
// 16 rows/block, 128 blocks.
__global__ __launch_bounds__(256, 2)
void ecgc_upd(const float* __restrict__ h_g,
              const float* __restrict__ ws,
              const float* __restrict__ U1_g,
              const float* __restrict__ b3_g,
              const float* __restrict__ U2_g,
              const float* __restrict__ b4_g,
              const float* __restrict__ gam_g,
              const float* __restrict__ bet_g,
              float*       __restrict__ out_g)
{
    const int bi0  = blockIdx.x * 16;
    const int t    = threadIdx.x;
    const int lane = t & 63;
    const int w    = t >> 6;
    const int m16  = lane & 15;
    const int quad = lane >> 4;

    __shared__ __align__(16) unsigned short shA[16 * APAD];    // 12.5 KB
    __shared__ __align__(16) unsigned short rbuf[16 * RPAD];   // 4.3 KB
    __shared__ float sh_s[4 * 16], sh_s2[4 * 16], sh_mu[16], sh_rs[16];

    // ---- stage A-tile: row = t>>4, q = t&15 covers cols [q*24, q*24+24) ----
    {
        const int row = t >> 4, q = t & 15;
        const float* hrow = h_g + (size_t)(bi0 + row) * DD;
        const float* wrow = ws  + (size_t)(bi0 + row) * 256;
        unsigned short tmp[24];
        #pragma unroll
        for (int c = 0; c < 24; ++c) {
            const int col = q * 24 + c;
            float v;
            if (col < 128)      v = hrow[col];
            else if (col < 256) v = wrow[col - 128];
            else                v = wrow[col - 256 + 128];
            tmp[c] = f2bf(v);
        }
        #pragma unroll
        for (int s8 = 0; s8 < 3; ++s8)
            *(short8*)&shA[row * APAD + q * 24 + s8 * 8] = *(const short8*)&tmp[s8 * 8];
    }
    __syncthreads();

    const int dstripe = w * 32;

    // ---- GEMM1: (16 x 384) @ (384 x 128) ----
    f32x4 acc[2] = {{0.f, 0.f, 0.f, 0.f}, {0.f, 0.f, 0.f, 0.f}};
    for (int kk = 0; kk < 12; ++kk) {
        const short8 a0 = *(const short8*)&shA[m16 * APAD + kk * 32 + quad * 8];
        #pragma unroll
        for (int dt = 0; dt < 2; ++dt) {
            const short8 b = ldb(U1_g, kk * 32 + quad * 8, dstripe + dt * 16 + m16);
            acc[dt] = __builtin_amdgcn_mfma_f32_16x16x32_bf16(a0, b, acc[dt], 0, 0, 0);
        }
    }

    // ---- relu + b3 -> rbuf (C->A transpose through LDS) ----
    #pragma unroll
    for (int dt = 0; dt < 2; ++dt) {
        const int d = dstripe + dt * 16 + m16;
        const float bb = b3_g[d];
        #pragma unroll
        for (int r = 0; r < 4; ++r) {
            const int ro = quad * 4 + r;
            rbuf[ro * RPAD + d] = f2bf(fmaxf(acc[dt][r] + bb, 0.f));
        }
    }
    __syncthreads();

    // ---- GEMM2: (16 x 128) @ (128 x 128) ----
    f32x4 acc2[2] = {{0.f, 0.f, 0.f, 0.f}, {0.f, 0.f, 0.f, 0.f}};
    for (int kk = 0; kk < 4; ++kk) {
        const short8 a0 = *(const short8*)&rbuf[m16 * RPAD + kk * 32 + quad * 8];
        #pragma unroll
        for (int dt = 0; dt < 2; ++dt) {
            const short8 b = ldb(U2_g, kk * 32 + quad * 8, dstripe + dt * 16 + m16);
            acc2[dt] = __builtin_amdgcn_mfma_f32_16x16x32_bf16(a0, b, acc2[dt], 0, 0, 0);
        }
    }

    // ---- x = h + upd + b4 ----
    float xv[2][4];
    #pragma unroll
    for (int dt = 0; dt < 2; ++dt) {
        const int d = dstripe + dt * 16 + m16;
        const float bb = b4_g[d];
        #pragma unroll
        for (int r = 0; r < 4; ++r) {
            const int ro = quad * 4 + r;
            xv[dt][r] = h_g[(size_t)(bi0 + ro) * DD + d] + acc2[dt][r] + bb;
        }
    }

    // ---- LN: reduce over the wave's 32-col stripe (16 lanes per row), then LDS ----
    #pragma unroll
    for (int r = 0; r < 4; ++r) {
        float s  = xv[0][r] + xv[1][r];
        float s2 = xv[0][r] * xv[0][r] + xv[1][r] * xv[1][r];
        #pragma unroll
        for (int off = 1; off < 16; off <<= 1) {
            s  += __shfl_xor(s,  off, 64);
            s2 += __shfl_xor(s2, off, 64);
        }
        if (m16 == 0) {
            const int ro = quad * 4 + r;
            sh_s[w * 16 + ro]  = s;
            sh_s2[w * 16 + ro] = s2;
        }
    }
    __syncthreads();
    if (t < 16) {
        const float S  = sh_s[t]  + sh_s[16 + t]  + sh_s[32 + t]  + sh_s[48 + t];
        const float S2 = sh_s2[t] + sh_s2[16 + t] + sh_s2[32 + t] + sh_s2[48 + t];
        const float mu  = S * (1.f / 128.f);
        const float var = S2 * (1.f / 128.f) - mu * mu;
        sh_mu[t] = mu;
        sh_rs[t] = rsqrtf(var + 1e-5f);
    }
    __syncthreads();

    #pragma unroll
    for (int dt = 0; dt < 2; ++dt) {
        const int d = dstripe + dt * 16 + m16;
        const float ga = gam_g[d], be = bet_g[d];
        #pragma unroll
        for (int r = 0; r < 4; ++r) {
            const int ro = quad * 4 + r;
            out_g[(size_t)(bi0 + ro) * DD + d] =
                (xv[dt][r] - sh_mu[ro]) * sh_rs[ro] * ga + be;
        }
    }
}

extern "C" void kernel_launch(void* const* d_in, const int* in_sizes, int n_in,
                              void* d_out, int out_size, void* d_ws, size_t ws_size,
                              hipStream_t stream) {
    float* ws = (float*)d_ws;   // 2048 * 256 floats = 2 MB
    ecgc_gate<<<8 * NN, 256, 0, stream>>>(
        (const float*)d_in[0],   // h
        (const float*)d_in[1],   // edge_feats
        (const int*)d_in[2],     // adj_mask
        (const float*)d_in[3],   // W1
        (const float*)d_in[4],   // b1
        (const float*)d_in[5],   // W2
        (const float*)d_in[6],   // b2
        ws);
    ecgc_upd<<<(8 * NN) / 16, 256, 0, stream>>>(
        (const float*)d_in[0],   // h
        ws,
        (const float*)d_in[7],   // U1
        (const float*)d_in[8],   // b3
        (const float*)d_in[9],   // U2
        (const float*)d_in[10],  // b4
        (const float*)d_in[11],  // gamma
        (const float*)d_in[12],  // beta
        (float*)d_out);
}

// Round 6
// 122.552 us; speedup vs baseline: 2.2822x; 1.0238x over previous
//
#include <hip/hip_runtime.h>
#include <hip/hip_bf16.h>
#include <math.h>

#define NN 256
#define DD 128
#define EE 64
#define APAD 392   // kernel2 A row stride (ushorts)
#define RPAD 136   // kernel2 rbuf row stride (ushorts)

typedef __attribute__((ext_vector_type(8))) short short8;
typedef __attribute__((ext_vector_type(4))) float f32x4;

static __device__ __forceinline__ unsigned short f2bf(float f) {
    __hip_bfloat16 b = __float2bfloat16(f);
    return *reinterpret_cast<unsigned short*>(&b);
}

// bf16 B-fragment for mfma_16x16x32 from row-major f32 B[K][128] in global.
static __device__ __forceinline__ short8 ldb(const float* __restrict__ B, int kbase, int d) {
    unsigned short tmp[8];
    #pragma unroll
    for (int j = 0; j < 8; ++j) tmp[j] = f2bf(B[(kbase + j) * DD + d]);
    return *(const short8*)tmp;
}

static __device__ __forceinline__ float sigm(float l) {
    return __fdividef(1.f, 1.f + __expf(-l));
}

// ---------------- Kernel 1: gate + masked aggregation (+ U1T/U2T packing) ----
// One block per (b,i). LDS ~8 KB. Barrier-free j-loop: each wave builds its own
// A-fragments in registers (T duplicated x4 -- buys zero hot-loop barriers).
__global__ __launch_bounds__(256, 4)
void ecgc_gate(const float* __restrict__ h_g,
               const float* __restrict__ ef_g,
               const int*   __restrict__ mask_g,
               const float* __restrict__ W1_g,
               const float* __restrict__ b1_g,
               const float* __restrict__ W2_g,
               const float* __restrict__ b2_g,
               const float* __restrict__ U1_g,
               const float* __restrict__ U2_g,
               float*          __restrict__ aggf,
               unsigned short* __restrict__ u1t,
               unsigned short* __restrict__ u2t)
{
    const int bi   = blockIdx.x;
    const int t    = threadIdx.x;
    const int lane = t & 63;
    const int w    = t >> 6;
    const int m16  = lane & 15;
    const int quad = lane >> 4;

    __shared__ __align__(16) float sh_ef4[NN * 4];   // 4 KB
    __shared__ __align__(16) float sh_q4[EE * 4];    // 1 KB {base,w10,w11,w12}
    __shared__ float sh_basep[4 * EE];               // 1 KB
    __shared__ float sh_w1e[3 * EE];
    __shared__ int   sh_jlist[NN], sh_wcnt[4], sh_cnt;

    // ---- U1T/U2T bf16 packing slice: 65536 elems over 2048 blocks ----
    if (t < 32) {
        const int flat = bi * 32 + t;
        if (flat < 384 * DD) {
            const int d = flat / 384, k = flat - d * 384;
            u1t[flat] = f2bf(U1_g[k * DD + d]);
        } else {
            const int f2 = flat - 384 * DD;
            const int d = f2 >> 7, k = f2 & 127;
            u2t[f2] = f2bf(U2_g[k * DD + d]);
        }
    }

    // ---- stage ----
    {
        const float* efr = ef_g + (size_t)bi * NN * 3;
        sh_ef4[t * 4 + 0] = efr[t * 3 + 0];
        sh_ef4[t * 4 + 1] = efr[t * 3 + 1];
        sh_ef4[t * 4 + 2] = efr[t * 3 + 2];
        sh_ef4[t * 4 + 3] = 0.f;
    }
    if (t < 192) sh_w1e[t] = W1_g[(DD + (t >> 6)) * EE + (t & 63)];

    const int mk = (mask_g[bi * NN + t] != 0) ? 1 : 0;
    const unsigned long long bal = __ballot(mk);
    if (lane == 0) sh_wcnt[w] = __popcll(bal);
    const int pre = __popcll(bal & ((1ull << lane) - 1ull));

    // basep: thread (e = t&63) partial over d-range [w*32, w*32+32)
    {
        const int e = t & 63;
        float acc = 0.f;
        #pragma unroll 8
        for (int d = w * 32; d < w * 32 + 32; ++d)
            acc = fmaf(h_g[bi * DD + d], W1_g[d * EE + e], acc);
        sh_basep[w * EE + e] = acc;
    }

    // W2 B-fragments in registers; b2 for C-init
    const int dstripe = w * 32;
    short8 bfrag[2][2];
    float  nb2[2];
    #pragma unroll
    for (int dt = 0; dt < 2; ++dt) {
        const int d = dstripe + 16 * dt + m16;
        nb2[dt] = b2_g[d];
        #pragma unroll
        for (int kh = 0; kh < 2; ++kh)
            bfrag[dt][kh] = ldb(W2_g, kh * 32 + quad * 8, d);
    }
    __syncthreads();   // barrier 1: wcnt/basep/w1e ready

    {
        int wbase = 0;
        for (int ww = 0; ww < w; ++ww) wbase += sh_wcnt[ww];
        if (mk) sh_jlist[wbase + pre] = t;
        if (t == 0) sh_cnt = sh_wcnt[0] + sh_wcnt[1] + sh_wcnt[2] + sh_wcnt[3];
    }
    if (t < EE) {
        const float base = b1_g[t] + sh_basep[t] + sh_basep[EE + t] +
                           sh_basep[2 * EE + t] + sh_basep[3 * EE + t];
        sh_q4[t * 4 + 0] = base;
        sh_q4[t * 4 + 1] = sh_w1e[t];
        sh_q4[t * 4 + 2] = sh_w1e[EE + t];
        sh_q4[t * 4 + 3] = sh_w1e[2 * EE + t];
    }
    __syncthreads();   // barrier 2: jlist/q4 ready.  Hot loop is barrier-free.

    // per-lane register cache of {base,w1e} for this lane's 16 e-values
    f32x4 qa[8], qb[8];
    #pragma unroll
    for (int jj = 0; jj < 8; ++jj) {
        qa[jj] = *(const f32x4*)&sh_q4[(quad * 8 + jj) * 4];
        qb[jj] = *(const f32x4*)&sh_q4[(32 + quad * 8 + jj) * 4];
    }

    const int cnt = sh_cnt;
    const int njt = (cnt + 15) >> 4;

    float sum2[2] = {0.f, 0.f};
    float mxl[2]  = {-3.0e38f, -3.0e38f};
    float mnl[2]  = { 3.0e38f,  3.0e38f};

    for (int jt = 0; jt < njt; ++jt) {
        const int row = jt * 16 + m16;          // < 256 always
        int jl = sh_jlist[row];
        jl = (row < cnt) ? jl : 0;              // clamp stale tail values
        const float4 efv = *(const float4*)&sh_ef4[jl * 4];

        // build A fragments in registers: a0 = e[quad*8..+8), a1 = e[32+quad*8..+8)
        union { short8 s; __hip_bfloat162 h2[4]; } ua, ub;
        #pragma unroll
        for (int p = 0; p < 4; ++p) {
            const f32x4 qa0 = qa[2 * p], qa1 = qa[2 * p + 1];
            const f32x4 qb0 = qb[2 * p], qb1 = qb[2 * p + 1];
            float2 va, vb;
            va.x = fmaxf(fmaf(efv.z, qa0[3], fmaf(efv.y, qa0[2], fmaf(efv.x, qa0[1], qa0[0]))), 0.f);
            va.y = fmaxf(fmaf(efv.z, qa1[3], fmaf(efv.y, qa1[2], fmaf(efv.x, qa1[1], qa1[0]))), 0.f);
            vb.x = fmaxf(fmaf(efv.z, qb0[3], fmaf(efv.y, qb0[2], fmaf(efv.x, qb0[1], qb0[0]))), 0.f);
            vb.y = fmaxf(fmaf(efv.z, qb1[3], fmaf(efv.y, qb1[2], fmaf(efv.x, qb1[1], qb1[0]))), 0.f);
            ua.h2[p] = __float22bfloat162_rn(va);
            ub.h2[p] = __float22bfloat162_rn(vb);
        }

        const bool tail = (jt == njt - 1) && (cnt & 15);
        #pragma unroll
        for (int dt = 0; dt < 2; ++dt) {
            f32x4 acc = {nb2[dt], nb2[dt], nb2[dt], nb2[dt]};
            acc = __builtin_amdgcn_mfma_f32_16x16x32_bf16(ua.s, bfrag[dt][0], acc, 0, 0, 0);
            acc = __builtin_amdgcn_mfma_f32_16x16x32_bf16(ub.s, bfrag[dt][1], acc, 0, 0, 0);
            if (!tail) {
                #pragma unroll
                for (int r = 0; r < 4; ++r) {
                    const float l = acc[r];
                    mxl[dt] = fmaxf(mxl[dt], l);
                    mnl[dt] = fminf(mnl[dt], l);
                    sum2[dt] += sigm(l);
                }
            } else {
                #pragma unroll
                for (int r = 0; r < 4; ++r) {
                    const bool v = (jt * 16 + quad * 4 + r) < cnt;
                    const float lx = v ? acc[r] : -3.0e38f;   // g(lx)=0, never wins max
                    const float ln = v ? acc[r] :  3.0e38f;   // never wins min
                    mxl[dt] = fmaxf(mxl[dt], lx);
                    mnl[dt] = fminf(mnl[dt], ln);
                    sum2[dt] += sigm(lx);
                }
            }
        }
    }

    // cross-quad reduce; sigmoid applied once on extreme logits (monotone)
    #pragma unroll
    for (int dt = 0; dt < 2; ++dt) {
        float s = sum2[dt], M = mxl[dt], m2 = mnl[dt];
        s += __shfl_xor(s, 16, 64);  s += __shfl_xor(s, 32, 64);
        M  = fmaxf(M,  __shfl_xor(M, 16, 64));  M  = fmaxf(M,  __shfl_xor(M, 32, 64));
        m2 = fminf(m2, __shfl_xor(m2, 16, 64)); m2 = fminf(m2, __shfl_xor(m2, 32, 64));
        if (quad == 0) {
            const int d = dstripe + 16 * dt + m16;
            const float hd = h_g[bi * DD + d];
            float mean = 0.f, amax = 0.f;
            if (cnt > 0) {
                mean = hd * s * __fdividef(1.f, (float)cnt);
                amax = (hd >= 0.f) ? hd * sigm(M) : hd * sigm(m2);
            }
            aggf[bi * 256 + d]       = mean;
            aggf[bi * 256 + 128 + d] = amax;
        }
    }
}

// ---------------- Kernel 2: batched update MLP + LayerNorm ----------------
// 16 rows/block, 128 blocks. B-matrices pre-packed bf16 (u1t[d][k], u2t[d][k]).
__global__ __launch_bounds__(256, 2)
void ecgc_upd(const float* __restrict__ h_g,
              const float* __restrict__ aggf,
              const unsigned short* __restrict__ u1t,
              const unsigned short* __restrict__ u2t,
              const float* __restrict__ b3_g,
              const float* __restrict__ b4_g,
              const float* __restrict__ gam_g,
              const float* __restrict__ bet_g,
              float*       __restrict__ out_g)
{
    const int bi0  = blockIdx.x * 16;
    const int t    = threadIdx.x;
    const int lane = t & 63;
    const int w    = t >> 6;
    const int m16  = lane & 15;
    const int quad = lane >> 4;

    __shared__ __align__(16) unsigned short shA[16 * APAD];    // 12.5 KB
    __shared__ __align__(16) unsigned short rbuf[16 * RPAD];   // 4.3 KB
    __shared__ float sh_s[4 * 16], sh_s2[4 * 16], sh_mu[16], sh_rs[16];

    // stage A-tile: row = t>>4, q = t&15 covers cols [q*24, q*24+24)
    {
        const int row = t >> 4, q = t & 15;
        const float* hrow = h_g  + (size_t)(bi0 + row) * DD;
        const float* wrow = aggf + (size_t)(bi0 + row) * 256;
        unsigned short tmp[24];
        #pragma unroll
        for (int c = 0; c < 24; ++c) {
            const int col = q * 24 + c;
            float v;
            if (col < 128)      v = hrow[col];
            else if (col < 256) v = wrow[col - 128];
            else                v = wrow[col - 256 + 128];
            tmp[c] = f2bf(v);
        }
        #pragma unroll
        for (int s8 = 0; s8 < 3; ++s8)
            *(short8*)&shA[row * APAD + q * 24 + s8 * 8] = *(const short8*)&tmp[s8 * 8];
    }
    __syncthreads();

    const int dstripe = w * 32;

    // GEMM1: (16 x 384) @ (384 x 128); b3 folded into C-init
    f32x4 acc[2];
    #pragma unroll
    for (int dt = 0; dt < 2; ++dt) {
        const float bb = b3_g[dstripe + dt * 16 + m16];
        acc[dt] = (f32x4){bb, bb, bb, bb};
    }
    for (int kk = 0; kk < 12; ++kk) {
        const short8 a0 = *(const short8*)&shA[m16 * APAD + kk * 32 + quad * 8];
        #pragma unroll
        for (int dt = 0; dt < 2; ++dt) {
            const int d = dstripe + dt * 16 + m16;
            const short8 b = *(const short8*)&u1t[(size_t)d * 384 + kk * 32 + quad * 8];
            acc[dt] = __builtin_amdgcn_mfma_f32_16x16x32_bf16(a0, b, acc[dt], 0, 0, 0);
        }
    }

    // relu -> rbuf (C->A transpose through LDS)
    #pragma unroll
    for (int dt = 0; dt < 2; ++dt) {
        const int d = dstripe + dt * 16 + m16;
        #pragma unroll
        for (int r = 0; r < 4; ++r) {
            const int ro = quad * 4 + r;
            rbuf[ro * RPAD + d] = f2bf(fmaxf(acc[dt][r], 0.f));
        }
    }
    __syncthreads();

    // GEMM2: (16 x 128) @ (128 x 128); b4 folded into C-init
    f32x4 acc2[2];
    #pragma unroll
    for (int dt = 0; dt < 2; ++dt) {
        const float bb = b4_g[dstripe + dt * 16 + m16];
        acc2[dt] = (f32x4){bb, bb, bb, bb};
    }
    for (int kk = 0; kk < 4; ++kk) {
        const short8 a0 = *(const short8*)&rbuf[m16 * RPAD + kk * 32 + quad * 8];
        #pragma unroll
        for (int dt = 0; dt < 2; ++dt) {
            const int d = dstripe + dt * 16 + m16;
            const short8 b = *(const short8*)&u2t[(size_t)d * 128 + kk * 32 + quad * 8];
            acc2[dt] = __builtin_amdgcn_mfma_f32_16x16x32_bf16(a0, b, acc2[dt], 0, 0, 0);
        }
    }

    // x = h + upd
    float xv[2][4];
    #pragma unroll
    for (int dt = 0; dt < 2; ++dt) {
        const int d = dstripe + dt * 16 + m16;
        #pragma unroll
        for (int r = 0; r < 4; ++r) {
            const int ro = quad * 4 + r;
            xv[dt][r] = h_g[(size_t)(bi0 + ro) * DD + d] + acc2[dt][r];
        }
    }

    // LayerNorm
    #pragma unroll
    for (int r = 0; r < 4; ++r) {
        float s  = xv[0][r] + xv[1][r];
        float s2 = xv[0][r] * xv[0][r] + xv[1][r] * xv[1][r];
        #pragma unroll
        for (int off = 1; off < 16; off <<= 1) {
            s  += __shfl_xor(s,  off, 64);
            s2 += __shfl_xor(s2, off, 64);
        }
        if (m16 == 0) {
            const int ro = quad * 4 + r;
            sh_s[w * 16 + ro]  = s;
            sh_s2[w * 16 + ro] = s2;
        }
    }
    __syncthreads();
    if (t < 16) {
        const float S  = sh_s[t]  + sh_s[16 + t]  + sh_s[32 + t]  + sh_s[48 + t];
        const float S2 = sh_s2[t] + sh_s2[16 + t] + sh_s2[32 + t] + sh_s2[48 + t];
        const float mu  = S * (1.f / 128.f);
        const float var = S2 * (1.f / 128.f) - mu * mu;
        sh_mu[t] = mu;
        sh_rs[t] = rsqrtf(var + 1e-5f);
    }
    __syncthreads();

    #pragma unroll
    for (int dt = 0; dt < 2; ++dt) {
        const int d = dstripe + dt * 16 + m16;
        const float ga = gam_g[d], be = bet_g[d];
        #pragma unroll
        for (int r = 0; r < 4; ++r) {
            const int ro = quad * 4 + r;
            out_g[(size_t)(bi0 + ro) * DD + d] =
                (xv[dt][r] - sh_mu[ro]) * sh_rs[ro] * ga + be;
        }
    }
}

extern "C" void kernel_launch(void* const* d_in, const int* in_sizes, int n_in,
                              void* d_out, int out_size, void* d_ws, size_t ws_size,
                              hipStream_t stream) {
    float* aggf = (float*)d_ws;                                    // 2048*256 f32 = 2 MB
    unsigned short* u1t = (unsigned short*)((char*)d_ws + (size_t)2048 * 256 * 4);
    unsigned short* u2t = u1t + 384 * DD;                          // +96 KB, +32 KB
    ecgc_gate<<<8 * NN, 256, 0, stream>>>(
        (const float*)d_in[0],   // h
        (const float*)d_in[1],   // edge_feats
        (const int*)d_in[2],     // adj_mask
        (const float*)d_in[3],   // W1
        (const float*)d_in[4],   // b1
        (const float*)d_in[5],   // W2
        (const float*)d_in[6],   // b2
        (const float*)d_in[7],   // U1
        (const float*)d_in[9],   // U2
        aggf, u1t, u2t);
    ecgc_upd<<<(8 * NN) / 16, 256, 0, stream>>>(
        (const float*)d_in[0],   // h
        aggf, u1t, u2t,
        (const float*)d_in[8],   // b3
        (const float*)d_in[10],  // b4
        (const float*)d_in[11],  // gamma
        (const float*)d_in[12],  // beta
        (float*)d_out);
}